// Round 23
// baseline (312.692 us; speedup 1.0000x reference)
//
#include <hip/hip_runtime.h>
#include <hip/hip_fp16.h>

// BallQLoss: B=2, N=8192, K=16, radius=0.5, L1 norm, mean over (B,N,K).
// v15b: byte-identical resubmit of v15 (container flapped pre-push).
// v15: v14 with mask arrays replaced by NAMED SCALARS (mA0..3, mB0..3),
// w-dimension hand-unrolled. R20/R21 post-mortem: the 8-pair loop body was
// too big for the unroller, #pragma unroll didn't fire, m[w] stayed
// runtime-indexed -> local memory -> ~930 MB scratch RMW traffic (rule
// #20). Named scalars cannot be demoted regardless of unroller behavior.
// Structure unchanged: 512 blocks = 128 query-groups x 4 j-slices; block
// = 128 queries (2/lane) x 2048 candidates staged in LDS f16x2 planes ->
// broadcast reads HALVED vs v10 (R17-measured bottleneck). Gram-form f16
// math identical to v10 -> same decisions. K2/K3 = v10.

#define NQ   8192
#define NB   2
#define KNN  16
#define QPB  128                       // queries per block (2 per lane)
#define WAVES 8
#define THREADS 512
#define NBQ (NB * NQ)                  // 16384
#define GROUPS2 (NBQ / QPB)            // 128
#define SLICES 4
#define SL_PAIRS 1024                  // pairs per slice (2048 candidates)
#define WPP 128                        // pairs per wave (2 rounds of 64)
#define IDXROW 132                     // u8/row: 8 lists * 16 + 4 pad

static __device__ __forceinline__ unsigned pkrtz_u(float a, float b) {
    return __builtin_bit_cast(unsigned, __builtin_amdgcn_cvt_pkrtz(a, b));
}
static __device__ __forceinline__ __half2 u_as_h2(unsigned u) {
    return __builtin_bit_cast(__half2, u);
}
// one candidate PAIR, gram form: w = q.p + cn - q2 (packed f16).
// hit <=> w > 0; MISS bit = sign bit, merged into chain mm.
static __device__ __forceinline__ void bq_pair(unsigned xu, unsigned yu,
                                               unsigned zu, unsigned cu,
                                               __half2 qpx, __half2 qpy,
                                               __half2 qpz, __half2 q2p,
                                               unsigned& mm) {
    __half2 acc = __hsub2(u_as_h2(cu), q2p);          // cn - q2
    acc = __hfma2(u_as_h2(xu), qpx, acc);
    acc = __hfma2(u_as_h2(yu), qpy, acc);
    acc = __hfma2(u_as_h2(zu), qpz, acc);             // w
    mm = (__builtin_bit_cast(unsigned, acc) & 0x80008000u) | (mm >> 1);
}

__global__ __launch_bounds__(THREADS, 8)
void ballq_scan(const float* __restrict__ pc,
                unsigned short* __restrict__ wsIdx,
                unsigned char* __restrict__ wsCnt)
{
    __shared__ __align__(16) unsigned lx[SL_PAIRS];   // 4 KB each
    __shared__ __align__(16) unsigned ly[SL_PAIRS];
    __shared__ __align__(16) unsigned lz[SL_PAIRS];
    __shared__ __align__(16) unsigned lc[SL_PAIRS];   // cn plane
    __shared__ unsigned char s_idx[QPB][IDXROW];      // 16.9 KB (u8 locals)
    __shared__ unsigned char s_cnt[QPB][12];

    const int tid = threadIdx.x;
    const int l   = tid & 63;          // lane
    const int c   = tid >> 6;          // wave id
    const int s   = blockIdx.x & 3;    // j slice
    const int g   = blockIdx.x >> 2;   // query group 0..127
    const int b   = g >> 6;            // batch
    const int qa  = (g & 63) * QPB + l;        // query A (in-batch index)
    const int qb  = qa + 64;                   // query B

    const float* __restrict__ pcb = pc + (size_t)b * NQ * 3;
    const float2* __restrict__ f2 = (const float2*)pcb;

    // ---- stage slice pairs + cn plane into LDS (f16x2) ----
    for (int p = tid; p < SL_PAIRS; p += THREADS) {
        const int gp = s * SL_PAIRS + p;
        const float2 v0 = f2[3 * gp + 0];   // (x_e, y_e)
        const float2 v1 = f2[3 * gp + 1];   // (z_e, x_o)
        const float2 v2 = f2[3 * gp + 2];   // (y_o, z_o)
        lx[p] = pkrtz_u(v0.x, v1.y);
        ly[p] = pkrtz_u(v0.y, v2.x);
        lz[p] = pkrtz_u(v1.x, v2.y);
        const float ne = v0.x * v0.x + v0.y * v0.y + v1.x * v1.x;
        const float no = v1.y * v1.y + v2.x * v2.x + v2.y * v2.y;
        lc[p] = pkrtz_u(0.125f - 0.5f * ne, 0.125f - 0.5f * no);
    }

    // query A registers
    const float ax = pcb[qa * 3 + 0], ay = pcb[qa * 3 + 1], az = pcb[qa * 3 + 2];
    const __half2 apx = u_as_h2(pkrtz_u(ax, ax));
    const __half2 apy = u_as_h2(pkrtz_u(ay, ay));
    const __half2 apz = u_as_h2(pkrtz_u(az, az));
    const float a2 = 0.5f * (ax * ax + ay * ay + az * az);
    const __half2 a2p = u_as_h2(pkrtz_u(a2, a2));
    // query B registers
    const float bx = pcb[qb * 3 + 0], by = pcb[qb * 3 + 1], bz = pcb[qb * 3 + 2];
    const __half2 bpx = u_as_h2(pkrtz_u(bx, bx));
    const __half2 bpy = u_as_h2(pkrtz_u(by, by));
    const __half2 bpz = u_as_h2(pkrtz_u(bz, bz));
    const float b2 = 0.5f * (bx * bx + by * by + bz * bz);
    const __half2 b2p = u_as_h2(pkrtz_u(b2, b2));

    __syncthreads();

    // ---- scan: wave c owns pairs [c*WPP, +WPP), 2 rounds of 64 ----
    int cntA = 0, cntB = 0;
    for (int r = 0; r < WPP / 64; ++r) {
        if (cntA >= KNN && cntB >= KNN) break;
        const int pbase = c * WPP + r * 64;
        // NAMED scalar mask chains — cannot be demoted to scratch
        unsigned mA0 = 0u, mA1 = 0u, mA2 = 0u, mA3 = 0u;
        unsigned mB0 = 0u, mB1 = 0u, mB2 = 0u, mB3 = 0u;
#pragma unroll
        for (int g4 = 0; g4 < 4; ++g4) {
            const int p0 = pbase + g4 * 4;
            {   // w = 0 -> mA0/mB0
                const uint4 X = *(const uint4*)&lx[p0];
                const uint4 Y = *(const uint4*)&ly[p0];
                const uint4 Z = *(const uint4*)&lz[p0];
                const uint4 C = *(const uint4*)&lc[p0];
                bq_pair(X.x, Y.x, Z.x, C.x, apx, apy, apz, a2p, mA0);
                bq_pair(X.y, Y.y, Z.y, C.y, apx, apy, apz, a2p, mA0);
                bq_pair(X.z, Y.z, Z.z, C.z, apx, apy, apz, a2p, mA0);
                bq_pair(X.w, Y.w, Z.w, C.w, apx, apy, apz, a2p, mA0);
                bq_pair(X.x, Y.x, Z.x, C.x, bpx, bpy, bpz, b2p, mB0);
                bq_pair(X.y, Y.y, Z.y, C.y, bpx, bpy, bpz, b2p, mB0);
                bq_pair(X.z, Y.z, Z.z, C.z, bpx, bpy, bpz, b2p, mB0);
                bq_pair(X.w, Y.w, Z.w, C.w, bpx, bpy, bpz, b2p, mB0);
            }
            {   // w = 1 -> mA1/mB1
                const int p1 = p0 + 16;
                const uint4 X = *(const uint4*)&lx[p1];
                const uint4 Y = *(const uint4*)&ly[p1];
                const uint4 Z = *(const uint4*)&lz[p1];
                const uint4 C = *(const uint4*)&lc[p1];
                bq_pair(X.x, Y.x, Z.x, C.x, apx, apy, apz, a2p, mA1);
                bq_pair(X.y, Y.y, Z.y, C.y, apx, apy, apz, a2p, mA1);
                bq_pair(X.z, Y.z, Z.z, C.z, apx, apy, apz, a2p, mA1);
                bq_pair(X.w, Y.w, Z.w, C.w, apx, apy, apz, a2p, mA1);
                bq_pair(X.x, Y.x, Z.x, C.x, bpx, bpy, bpz, b2p, mB1);
                bq_pair(X.y, Y.y, Z.y, C.y, bpx, bpy, bpz, b2p, mB1);
                bq_pair(X.z, Y.z, Z.z, C.z, bpx, bpy, bpz, b2p, mB1);
                bq_pair(X.w, Y.w, Z.w, C.w, bpx, bpy, bpz, b2p, mB1);
            }
            {   // w = 2 -> mA2/mB2
                const int p2 = p0 + 32;
                const uint4 X = *(const uint4*)&lx[p2];
                const uint4 Y = *(const uint4*)&ly[p2];
                const uint4 Z = *(const uint4*)&lz[p2];
                const uint4 C = *(const uint4*)&lc[p2];
                bq_pair(X.x, Y.x, Z.x, C.x, apx, apy, apz, a2p, mA2);
                bq_pair(X.y, Y.y, Z.y, C.y, apx, apy, apz, a2p, mA2);
                bq_pair(X.z, Y.z, Z.z, C.z, apx, apy, apz, a2p, mA2);
                bq_pair(X.w, Y.w, Z.w, C.w, apx, apy, apz, a2p, mA2);
                bq_pair(X.x, Y.x, Z.x, C.x, bpx, bpy, bpz, b2p, mB2);
                bq_pair(X.y, Y.y, Z.y, C.y, bpx, bpy, bpz, b2p, mB2);
                bq_pair(X.z, Y.z, Z.z, C.z, bpx, bpy, bpz, b2p, mB2);
                bq_pair(X.w, Y.w, Z.w, C.w, bpx, bpy, bpz, b2p, mB2);
            }
            {   // w = 3 -> mA3/mB3
                const int p3 = p0 + 48;
                const uint4 X = *(const uint4*)&lx[p3];
                const uint4 Y = *(const uint4*)&ly[p3];
                const uint4 Z = *(const uint4*)&lz[p3];
                const uint4 C = *(const uint4*)&lc[p3];
                bq_pair(X.x, Y.x, Z.x, C.x, apx, apy, apz, a2p, mA3);
                bq_pair(X.y, Y.y, Z.y, C.y, apx, apy, apz, a2p, mA3);
                bq_pair(X.z, Y.z, Z.z, C.z, apx, apy, apz, a2p, mA3);
                bq_pair(X.w, Y.w, Z.w, C.w, apx, apy, apz, a2p, mA3);
                bq_pair(X.x, Y.x, Z.x, C.x, bpx, bpy, bpz, b2p, mB3);
                bq_pair(X.y, Y.y, Z.y, C.y, bpx, bpy, bpz, b2p, mB3);
                bq_pair(X.z, Y.z, Z.z, C.z, bpx, bpy, bpz, b2p, mB3);
                bq_pair(X.w, Y.w, Z.w, C.w, bpx, bpy, bpz, b2p, mB3);
            }
        }
        const int lb = r * 128;   // local cand base within wave chunk

        // ---- extract A (ascending j) ----
        if ((mA0 & mA1 & mA2 & mA3) != 0xFFFFFFFFu && cntA < KNN) {
            const unsigned h0 = ~mA0, h1 = ~mA1, h2 = ~mA2, h3 = ~mA3;
            unsigned long long ev =
                  (unsigned long long)(h0 & 0xFFFFu)
                | ((unsigned long long)(h1 & 0xFFFFu) << 16)
                | ((unsigned long long)(h2 & 0xFFFFu) << 32)
                | ((unsigned long long)(h3 & 0xFFFFu) << 48);
            unsigned long long od =
                  (unsigned long long)(h0 >> 16)
                | ((unsigned long long)(h1 >> 16) << 16)
                | ((unsigned long long)(h2 >> 16) << 32)
                | ((unsigned long long)(h3 >> 16) << 48);
            while ((ev | od) && cntA < KNN) {
                const int pe = ev ? __builtin_ctzll(ev) : 127;
                const int po = od ? __builtin_ctzll(od) : 127;
                int lo;
                if (pe <= po) { lo = lb + 2 * pe;     ev &= ev - 1; }
                else          { lo = lb + 2 * po + 1; od &= od - 1; }
                s_idx[l][c * KNN + cntA] = (unsigned char)lo;
                ++cntA;
            }
        }
        // ---- extract B (ascending j) ----
        if ((mB0 & mB1 & mB2 & mB3) != 0xFFFFFFFFu && cntB < KNN) {
            const unsigned h0 = ~mB0, h1 = ~mB1, h2 = ~mB2, h3 = ~mB3;
            unsigned long long ev =
                  (unsigned long long)(h0 & 0xFFFFu)
                | ((unsigned long long)(h1 & 0xFFFFu) << 16)
                | ((unsigned long long)(h2 & 0xFFFFu) << 32)
                | ((unsigned long long)(h3 & 0xFFFFu) << 48);
            unsigned long long od =
                  (unsigned long long)(h0 >> 16)
                | ((unsigned long long)(h1 >> 16) << 16)
                | ((unsigned long long)(h2 >> 16) << 32)
                | ((unsigned long long)(h3 >> 16) << 48);
            while ((ev | od) && cntB < KNN) {
                const int pe = ev ? __builtin_ctzll(ev) : 127;
                const int po = od ? __builtin_ctzll(od) : 127;
                int lo;
                if (pe <= po) { lo = lb + 2 * pe;     ev &= ev - 1; }
                else          { lo = lb + 2 * po + 1; od &= od - 1; }
                s_idx[l + 64][c * KNN + cntB] = (unsigned char)lo;
                ++cntB;
            }
        }
    }
    s_cnt[l][c]      = (unsigned char)cntA;
    s_cnt[l + 64][c] = (unsigned char)cntB;
    __syncthreads();

    // ---- merge (waves 0,1; lane = query row): first <=16 this slice ----
    if (c < 2) {
        const int row = c * 64 + l;            // 0..127
        const int qid = g * QPB + row;         // 0..16383
        unsigned short* __restrict__ rp =
            wsIdx + ((size_t)s * NBQ + qid) * KNN;
        const int jb = s * (2 * SL_PAIRS);     // slice cand base
        int outc = 0;
        for (int c2 = 0; c2 < WAVES && outc < KNN; ++c2) {
            const int f = s_cnt[row][c2];
            const int take = f < (KNN - outc) ? f : (KNN - outc);
            const int wb = jb + c2 * 256;      // wave chunk cand base
            for (int t = 0; t < take; ++t)
                rp[outc++] = (unsigned short)(wb + s_idx[row][c2 * KNN + t]);
        }
        wsCnt[qid * 4 + s] = (unsigned char)outc;
    }
}

__global__ __launch_bounds__(256)
void ballq_loss(const float* __restrict__ flow,
                const unsigned short* __restrict__ wsIdx,
                const unsigned char* __restrict__ wsCnt,
                float* __restrict__ partial)
{
    const int tid = blockIdx.x * 256 + threadIdx.x;
    const int qid = tid >> 4;          // one query per 16 lanes
    const int t   = tid & 15;          // k-slot
    const int b   = qid >> 13;
    const int iq  = qid & (NQ - 1);
    const float* __restrict__ flb = flow + (size_t)b * NQ * 3;

    const unsigned cw = *(const unsigned*)(wsCnt + qid * 4);
    const int b0 = cw & 0xFF;
    const int b1 = (cw >> 8)  & 0xFF;
    const int b2 = (cw >> 16) & 0xFF;
    const int c1 = b0, c2c = b0 + b1, c3 = b0 + b1 + b2;
    int tot = c3 + ((cw >> 24) & 0xFF);
    if (tot > KNN) tot = KNN;

    const int seff = (t < tot) ? t : 0;   // padded slots -> first neighbor
    const int sl   = (seff >= c1) + (seff >= c2c) + (seff >= c3);
    const int cum  = (sl == 0) ? 0 : (sl == 1) ? c1 : (sl == 2) ? c2c : c3;
    int j = wsIdx[((size_t)sl * NBQ + qid) * KNN + (seff - cum)];
    if (tot == 0) j = iq;   // pathological guard: self (diff = 0, = reference)

    const float fx = flb[iq * 3 + 0];
    const float fy = flb[iq * 3 + 1];
    const float fz = flb[iq * 3 + 2];
    float lo = fabsf(fx - flb[j * 3 + 0]) +
               fabsf(fy - flb[j * 3 + 1]) +
               fabsf(fz - flb[j * 3 + 2]);

    for (int o = 32; o > 0; o >>= 1)
        lo += __shfl_down(lo, o, 64);
    __shared__ float sred[4];
    if ((threadIdx.x & 63) == 0) sred[threadIdx.x >> 6] = lo;
    __syncthreads();
    if (threadIdx.x == 0)
        partial[blockIdx.x] = sred[0] + sred[1] + sred[2] + sred[3];
}

__global__ __launch_bounds__(1024)
void ballq_final(const float* __restrict__ partial, float* __restrict__ out)
{
    const int tid = threadIdx.x;       // 1024 threads, 16 waves
    float v = partial[tid];
    for (int o = 32; o > 0; o >>= 1)
        v += __shfl_down(v, o, 64);
    __shared__ float s[16];
    if ((tid & 63) == 0) s[tid >> 6] = v;
    __syncthreads();
    if (tid == 0) {
        float t = 0.0f;
#pragma unroll
        for (int w = 0; w < 16; ++w) t += s[w];
        out[0] = t * (1.0f / ((float)NB * NQ * KNN));
    }
}

extern "C" void kernel_launch(void* const* d_in, const int* in_sizes, int n_in,
                              void* d_out, int out_size, void* d_ws, size_t ws_size,
                              hipStream_t stream)
{
    (void)in_sizes; (void)n_in; (void)out_size; (void)ws_size;
    const float* pc   = (const float*)d_in[0];
    const float* flow = (const float*)d_in[1];
    float* out = (float*)d_out;

    // ws layout: idx lists (4 slices x 16384 q x 16 u16 = 2 MB),
    //            counts (16384 x 4 B), partials (1024 f32)
    unsigned short* wsIdx = (unsigned short*)d_ws;
    unsigned char*  wsCnt = (unsigned char*)d_ws + (size_t)SLICES * NBQ * KNN * 2;
    float* partial = (float*)(wsCnt + (size_t)NBQ * 4);

    ballq_scan<<<GROUPS2 * SLICES, THREADS, 0, stream>>>(pc, wsIdx, wsCnt);
    ballq_loss<<<NBQ * 16 / 256, 256, 0, stream>>>(flow, wsIdx, wsCnt, partial);
    ballq_final<<<1, 1024, 0, stream>>>(partial, out);
}

// Round 24
// 33.807 us; speedup vs baseline: 9.2493x; 9.2493x over previous
//
#include <hip/hip_runtime.h>
#include <hip/hip_fp16.h>

// BallQLoss: B=2, N=8192, K=16, radius=0.5, L1 norm, mean over (B,N,K).
// v16 = v10 EXACT REVERT (session best, 33.5us @ R16). The Q=2 direction
// (v13/v14/v15) hits an unexplained compiler scratch-materialization
// (~1 GB HBM RMW, 10x regression) regardless of mask representation;
// abandoned. v10: 3 kernels, plain stores, gram-form f16 eval (6 VALU per
// candidate pair), 4 LDS planes (x,y,z,cn packed f16x2), 1024 scan blocks
// = 256 query-groups x 4 j-slices, 8 waves/SIMD max occupancy.
// K1 scan: per-wave 128 pairs in 2 rounds; miss-bit chains; extraction in
// ascending j (pointnet2 first-K semantics); per-slice first-16 lists
// (u16) + count bytes -> d_ws.
// K2 loss: 16 lanes/query, slice-decode, padded slots -> first neighbor.
// K3 final: 1 block reduces 1024 partials -> mean. Replay-safe.

#define NQ   8192
#define NB   2
#define KNN  16
#define QPB  64
#define WAVES 8
#define THREADS (QPB * WAVES)          // 512
#define NBQ (NB * NQ)                  // 16384
#define GROUPS (NBQ / QPB)             // 256
#define SLICES 4
#define SL_PAIRS 1024                  // pairs per slice (2048 candidates)
#define WPP 128                        // pairs per wave (2 rounds of 64)
#define IDXROW 130                     // u16/row: 8 lists * 16 + 2 pad

static __device__ __forceinline__ unsigned pkrtz_u(float a, float b) {
    return __builtin_bit_cast(unsigned, __builtin_amdgcn_cvt_pkrtz(a, b));
}
static __device__ __forceinline__ __half2 u_as_h2(unsigned u) {
    return __builtin_bit_cast(__half2, u);
}
// one candidate PAIR, gram form: w = q.p + cn - q2 (packed f16).
// hit <=> w > 0; MISS bit = sign bit, merged into chain mm.
static __device__ __forceinline__ void bq_pair(unsigned xu, unsigned yu,
                                               unsigned zu, unsigned cu,
                                               __half2 qpx, __half2 qpy,
                                               __half2 qpz, __half2 q2p,
                                               unsigned& mm) {
    __half2 acc = __hsub2(u_as_h2(cu), q2p);          // cn - q2
    acc = __hfma2(u_as_h2(xu), qpx, acc);
    acc = __hfma2(u_as_h2(yu), qpy, acc);
    acc = __hfma2(u_as_h2(zu), qpz, acc);             // w
    mm = (__builtin_bit_cast(unsigned, acc) & 0x80008000u) | (mm >> 1);
}

__global__ __launch_bounds__(THREADS, 8)
void ballq_scan(const float* __restrict__ pc,
                unsigned short* __restrict__ wsIdx,
                unsigned char* __restrict__ wsCnt)
{
    __shared__ __align__(16) unsigned lx[SL_PAIRS];   // 4 KB each
    __shared__ __align__(16) unsigned ly[SL_PAIRS];
    __shared__ __align__(16) unsigned lz[SL_PAIRS];
    __shared__ __align__(16) unsigned lc[SL_PAIRS];   // cn plane
    __shared__ unsigned short s_idx[QPB][IDXROW];     // 16.6 KB
    __shared__ unsigned char  s_cnt[QPB][12];

    const int tid = threadIdx.x;
    const int q   = tid & 63;          // lane = query slot
    const int c   = tid >> 6;          // wave id
    const int s   = blockIdx.x & 3;    // j slice
    const int g   = blockIdx.x >> 2;   // query group 0..255
    const int b   = g >> 7;
    const int i   = (g & 127) * QPB + q;

    const float* __restrict__ pcb = pc + (size_t)b * NQ * 3;
    const float2* __restrict__ f2 = (const float2*)pcb;

    // ---- stage slice pairs + cn plane into LDS (f16x2) ----
    for (int p = tid; p < SL_PAIRS; p += THREADS) {
        const int gp = s * SL_PAIRS + p;
        const float2 v0 = f2[3 * gp + 0];   // (x_e, y_e)
        const float2 v1 = f2[3 * gp + 1];   // (z_e, x_o)
        const float2 v2 = f2[3 * gp + 2];   // (y_o, z_o)
        lx[p] = pkrtz_u(v0.x, v1.y);
        ly[p] = pkrtz_u(v0.y, v2.x);
        lz[p] = pkrtz_u(v1.x, v2.y);
        const float ne = v0.x * v0.x + v0.y * v0.y + v1.x * v1.x;
        const float no = v1.y * v1.y + v2.x * v2.x + v2.y * v2.y;
        lc[p] = pkrtz_u(0.125f - 0.5f * ne, 0.125f - 0.5f * no);
    }

    const float qx = pcb[i * 3 + 0];
    const float qy = pcb[i * 3 + 1];
    const float qz = pcb[i * 3 + 2];
    const __half2 qpx = u_as_h2(pkrtz_u(qx, qx));
    const __half2 qpy = u_as_h2(pkrtz_u(qy, qy));
    const __half2 qpz = u_as_h2(pkrtz_u(qz, qz));
    const float q2 = 0.5f * (qx * qx + qy * qy + qz * qz);
    const __half2 q2p = u_as_h2(pkrtz_u(q2, q2));

    __syncthreads();

    // ---- scan: wave c owns pairs [c*WPP, c*WPP+WPP), 2 rounds of 64 ----
    int cnt = 0;
    for (int r = 0; r < WPP / 64 && cnt < KNN; ++r) {
        const int pbase = c * WPP + r * 64;
        unsigned m[4] = {0u, 0u, 0u, 0u};   // MISS bit chains
#pragma unroll
        for (int g4 = 0; g4 < 4; ++g4) {
#pragma unroll
            for (int w = 0; w < 4; ++w) {
                const int pb = pbase + w * 16 + g4 * 4;
                const uint4 X = *(const uint4*)&lx[pb];  // broadcast b128
                const uint4 Y = *(const uint4*)&ly[pb];
                const uint4 Z = *(const uint4*)&lz[pb];
                const uint4 C = *(const uint4*)&lc[pb];
                bq_pair(X.x, Y.x, Z.x, C.x, qpx, qpy, qpz, q2p, m[w]);
                bq_pair(X.y, Y.y, Z.y, C.y, qpx, qpy, qpz, q2p, m[w]);
                bq_pair(X.z, Y.z, Z.z, C.z, qpx, qpy, qpz, q2p, m[w]);
                bq_pair(X.w, Y.w, Z.w, C.w, qpx, qpy, qpz, q2p, m[w]);
            }
        }
        // all-miss fast path
        if ((m[0] & m[1] & m[2] & m[3]) == 0xFFFFFFFFu) continue;
        const unsigned h0 = ~m[0], h1 = ~m[1], h2m = ~m[2], h3 = ~m[3];

        // bit n of ev/od = pair (pbase+n) even/odd candidate (hit bits)
        unsigned long long ev =
              (unsigned long long)(h0 & 0xFFFFu)
            | ((unsigned long long)(h1 & 0xFFFFu) << 16)
            | ((unsigned long long)(h2m & 0xFFFFu) << 32)
            | ((unsigned long long)(h3 & 0xFFFFu) << 48);
        unsigned long long od =
              (unsigned long long)(h0 >> 16)
            | ((unsigned long long)(h1 >> 16) << 16)
            | ((unsigned long long)(h2m >> 16) << 32)
            | ((unsigned long long)(h3 >> 16) << 48);

        const int jb = s * (2 * SL_PAIRS) + 2 * pbase;
        while ((ev | od) && cnt < KNN) {
            const int pe = ev ? __builtin_ctzll(ev) : 127;
            const int po = od ? __builtin_ctzll(od) : 127;
            int j;
            if (pe <= po) { j = jb + 2 * pe;     ev &= ev - 1; }
            else          { j = jb + 2 * po + 1; od &= od - 1; }
            s_idx[q][c * KNN + cnt] = (unsigned short)j;
            ++cnt;
        }
    }
    s_cnt[q][c] = (unsigned char)cnt;
    __syncthreads();

    // ---- merge (wave 0, lane = query): first <=16 over this slice ----
    if (c == 0) {
        const int qid = g * QPB + q;   // 0..16383
        unsigned short* __restrict__ rp =
            wsIdx + ((size_t)s * NBQ + qid) * KNN;
        int outc = 0;
        for (int c2 = 0; c2 < WAVES && outc < KNN; ++c2) {
            const int f = s_cnt[q][c2];
            const int take = f < (KNN - outc) ? f : (KNN - outc);
            for (int t = 0; t < take; ++t)
                rp[outc++] = s_idx[q][c2 * KNN + t];
        }
        wsCnt[qid * 4 + s] = (unsigned char)outc;
    }
}

__global__ __launch_bounds__(256)
void ballq_loss(const float* __restrict__ flow,
                const unsigned short* __restrict__ wsIdx,
                const unsigned char* __restrict__ wsCnt,
                float* __restrict__ partial)
{
    const int tid = blockIdx.x * 256 + threadIdx.x;
    const int qid = tid >> 4;          // one query per 16 lanes
    const int t   = tid & 15;          // k-slot
    const int b   = qid >> 13;
    const int iq  = qid & (NQ - 1);
    const float* __restrict__ flb = flow + (size_t)b * NQ * 3;

    const unsigned cw = *(const unsigned*)(wsCnt + qid * 4);
    const int b0 = cw & 0xFF;
    const int b1 = (cw >> 8)  & 0xFF;
    const int b2 = (cw >> 16) & 0xFF;
    const int c1 = b0, c2c = b0 + b1, c3 = b0 + b1 + b2;
    int tot = c3 + ((cw >> 24) & 0xFF);
    if (tot > KNN) tot = KNN;

    const int seff = (t < tot) ? t : 0;   // padded slots -> first neighbor
    const int sl   = (seff >= c1) + (seff >= c2c) + (seff >= c3);
    const int cum  = (sl == 0) ? 0 : (sl == 1) ? c1 : (sl == 2) ? c2c : c3;
    int j = wsIdx[((size_t)sl * NBQ + qid) * KNN + (seff - cum)];
    if (tot == 0) j = iq;   // pathological guard: self (diff = 0, = reference)

    const float fx = flb[iq * 3 + 0];
    const float fy = flb[iq * 3 + 1];
    const float fz = flb[iq * 3 + 2];
    float lo = fabsf(fx - flb[j * 3 + 0]) +
               fabsf(fy - flb[j * 3 + 1]) +
               fabsf(fz - flb[j * 3 + 2]);

    for (int o = 32; o > 0; o >>= 1)
        lo += __shfl_down(lo, o, 64);
    __shared__ float sred[4];
    if ((threadIdx.x & 63) == 0) sred[threadIdx.x >> 6] = lo;
    __syncthreads();
    if (threadIdx.x == 0)
        partial[blockIdx.x] = sred[0] + sred[1] + sred[2] + sred[3];
}

__global__ __launch_bounds__(1024)
void ballq_final(const float* __restrict__ partial, float* __restrict__ out)
{
    const int tid = threadIdx.x;       // 1024 threads, 16 waves
    float v = partial[tid];
    for (int o = 32; o > 0; o >>= 1)
        v += __shfl_down(v, o, 64);
    __shared__ float s[16];
    if ((tid & 63) == 0) s[tid >> 6] = v;
    __syncthreads();
    if (tid == 0) {
        float t = 0.0f;
#pragma unroll
        for (int w = 0; w < 16; ++w) t += s[w];
        out[0] = t * (1.0f / ((float)NB * NQ * KNN));
    }
}

extern "C" void kernel_launch(void* const* d_in, const int* in_sizes, int n_in,
                              void* d_out, int out_size, void* d_ws, size_t ws_size,
                              hipStream_t stream)
{
    (void)in_sizes; (void)n_in; (void)out_size; (void)ws_size;
    const float* pc   = (const float*)d_in[0];
    const float* flow = (const float*)d_in[1];
    float* out = (float*)d_out;

    // ws layout: idx lists (4 slices x 16384 q x 16 u16 = 2 MB),
    //            counts (16384 x 4 B), partials (1024 f32)
    unsigned short* wsIdx = (unsigned short*)d_ws;
    unsigned char*  wsCnt = (unsigned char*)d_ws + (size_t)SLICES * NBQ * KNN * 2;
    float* partial = (float*)(wsCnt + (size_t)NBQ * 4);

    ballq_scan<<<GROUPS * SLICES, THREADS, 0, stream>>>(pc, wsIdx, wsCnt);
    ballq_loss<<<NBQ * 16 / 256, 256, 0, stream>>>(flow, wsIdx, wsCnt, partial);
    ballq_final<<<1, 1024, 0, stream>>>(partial, out);
}